// Round 4
// baseline (176.480 us; speedup 1.0000x reference)
//
#include <hip/hip_runtime.h>
#include <cmath>

#define H 1024
#define V 50257
#define L 512
#define MAXNB 1024

struct Args {
    const int* tok; const float* hid; const float* enc; const float* emb;
    const float* Wa; const float* ba; const float* Wc; const float* bcb;
    const float* Wih; const float* bih; const float* Whh; const float* bhh;
    const float* Wo; const float* bo;
    float* elg; float* gh; float* aa; float* xv; float* hn;
    float* pm; float* ps; unsigned* bar;
    float* out_logits; float* out_hnew; float* out_attnw;
};

__device__ __forceinline__ float wred_sum(float v) {
#pragma unroll
    for (int o = 32; o > 0; o >>= 1) v += __shfl_xor(v, o, 64);
    return v;
}
__device__ __forceinline__ float dot4(float4 a, float4 b) {
    return a.x * b.x + a.y * b.y + a.z * b.z + a.w * b.w;
}
__device__ __forceinline__ void ms_merge(float& m, float& s, float m2, float s2) {
    float M = fmaxf(m, m2);
    if (M == -INFINITY) { m = M; s = 0.f; return; }
    s = s * expf(m - M) + s2 * expf(m2 - M);
    m = M;
}

// Device-wide barrier: 16 counter stripes (128B apart) per phase, monotonic
// within a call, memset to 0 before each launch. Release-fence before arrive,
// acquire-fence after observe (cross-XCD L2 wb/inv via __threadfence).
__device__ __forceinline__ void gbar(unsigned* bar, int ph, unsigned nblk) {
    __syncthreads();
    if (threadIdx.x == 0) {
        __threadfence();
        unsigned* c = bar + ph * 512;         // 16 stripes x 32 uints
        __hip_atomic_fetch_add(&c[(blockIdx.x & 15) * 32], 1u,
                               __ATOMIC_RELAXED, __HIP_MEMORY_SCOPE_AGENT);
        unsigned sum;
        do {
            sum = 0;
#pragma unroll
            for (int i = 0; i < 16; ++i)
                sum += __hip_atomic_load(&c[i * 32], __ATOMIC_RELAXED,
                                         __HIP_MEMORY_SCOPE_AGENT);
            if (sum < nblk) __builtin_amdgcn_s_sleep(2);
        } while (sum < nblk);
        __threadfence();
    }
    __syncthreads();
}

__global__ __launch_bounds__(256, 4) void mega(Args args) {
    const int t = threadIdx.x, lane = t & 63, wv = t >> 6, b = blockIdx.x;
    const unsigned nblk = gridDim.x;
    const int nw = nblk * 4;              // wave count
    const int gw = b * 4 + wv;            // global wave id
    const float4* h4 = (const float4*)args.hid;
    const float4* e4 = (const float4*)(args.emb + (size_t)args.tok[0] * H);
    __shared__ float s_a[4], s_b[4], s_g[3][4];
    __shared__ float s_c;

    // ---- P0: attn logits (exp, no-max) + gh rows + zero aa -----------------
    for (int job = gw; job < 3588; job += nw) {
        if (job < 512) {
            const float4* wr = (const float4*)(args.Wa + (size_t)job * 2048);
            float acc = 0.f;
#pragma unroll
            for (int k = 0; k < 8; ++k) {
                int f = 64 * k + lane;
                float4 s = (f < 256) ? e4[f] : h4[f - 256];
                acc += dot4(wr[f], s);
            }
            acc = wred_sum(acc);
            if (lane == 0) args.elg[job] = expf(acc + args.ba[job]);
        } else if (job < 3584) {
            const int j = job - 512;
            const float4* wh = (const float4*)(args.Whh + (size_t)j * H);
            float acc = 0.f;
#pragma unroll
            for (int k = 0; k < 4; ++k) {
                int f = 64 * k + lane;
                acc += dot4(wh[f], h4[f]);
            }
            acc = wred_sum(acc);
            if (lane == 0) args.gh[j] = acc + args.bhh[j];
        } else {
            ((float4*)args.aa)[(job - 3584) * 64 + lane] =
                make_float4(0.f, 0.f, 0.f, 0.f);
        }
    }
    gbar(args.bar, 0, nblk);

    // ---- P1: aa = sum_l (elg_l/S) enc[l,:] (32 blocks, atomics); attnw -----
    if (b <= 32) {
        float e0 = args.elg[t], e1 = args.elg[t + 256];
        float s = wred_sum(e0 + e1);
        if (lane == 0) s_a[wv] = s;
        __syncthreads();
        const float invS = 1.f / (s_a[0] + s_a[1] + s_a[2] + s_a[3]);
        if (b < 32) {
            float4 a = make_float4(0.f, 0.f, 0.f, 0.f);
#pragma unroll 4
            for (int l = b * 16; l < b * 16 + 16; ++l) {
                const float w = args.elg[l] * invS;
                const float4 v = ((const float4*)(args.enc + (size_t)l * H))[t];
                a.x += w * v.x; a.y += w * v.y; a.z += w * v.z; a.w += w * v.w;
            }
            float* dst = args.aa + 4 * t;
            atomicAdd(dst + 0, a.x);
            atomicAdd(dst + 1, a.y);
            atomicAdd(dst + 2, a.z);
            atomicAdd(dst + 3, a.w);
        } else {
            args.out_attnw[t] = e0 * invS;
            args.out_attnw[t + 256] = e1 * invS;
        }
    }
    gbar(args.bar, 1, nblk);

    // ---- P2: x[j] = relu([emb, aa] . Wc[j,:] + bc[j]); block per row -------
    {
        const float4* a4 = (const float4*)args.aa;
        for (int j = b; j < H; j += nblk) {
            const float4* wr = (const float4*)(args.Wc + (size_t)j * 2048);
            float acc = dot4(wr[t], e4[t]) + dot4(wr[t + 256], a4[t]);
            acc = wred_sum(acc);
            if (lane == 0) s_a[wv] = acc;
            __syncthreads();
            if (t == 0)
                args.xv[j] = fmaxf(s_a[0] + s_a[1] + s_a[2] + s_a[3] +
                                   args.bcb[j], 0.f);
            __syncthreads();
        }
    }
    gbar(args.bar, 2, nblk);

    // ---- P3: gates + GRU; block per row ------------------------------------
    {
        const float4 xr = ((const float4*)args.xv)[t];
        for (int j = b; j < H; j += nblk) {
            float g0 = dot4(((const float4*)(args.Wih + (size_t)j * H))[t], xr);
            float g1 = dot4(((const float4*)(args.Wih + (size_t)(j + H) * H))[t], xr);
            float g2 = dot4(((const float4*)(args.Wih + (size_t)(j + 2 * H) * H))[t], xr);
            g0 = wred_sum(g0); g1 = wred_sum(g1); g2 = wred_sum(g2);
            if (lane == 0) { s_g[0][wv] = g0; s_g[1][wv] = g1; s_g[2][wv] = g2; }
            __syncthreads();
            if (t == 0) {
                float G0 = s_g[0][0] + s_g[0][1] + s_g[0][2] + s_g[0][3] + args.bih[j];
                float G1 = s_g[1][0] + s_g[1][1] + s_g[1][2] + s_g[1][3] + args.bih[j + H];
                float G2 = s_g[2][0] + s_g[2][1] + s_g[2][2] + s_g[2][3] + args.bih[j + 2 * H];
                float r = 1.f / (1.f + expf(-(G0 + args.gh[j])));
                float z = 1.f / (1.f + expf(-(G1 + args.gh[j + H])));
                float n = tanhf(G2 + r * args.gh[j + 2 * H]);
                float hv = (1.f - z) * n + z * args.hid[j];
                args.hn[j] = hv;
                args.out_hnew[j] = hv;
            }
            __syncthreads();
        }
    }
    gbar(args.bar, 3, nblk);

    // ---- P4: logits = hn . Wo[v,:] + bo; online (m,s) per wave -------------
    {
        float4 hreg[4];
#pragma unroll
        for (int k = 0; k < 4; ++k) hreg[k] = ((const float4*)args.hn)[64 * k + lane];
        float m = -INFINITY, s = 0.f;
        for (int v = gw; v < V; v += nw) {
            const float4* wr = (const float4*)(args.Wo + (size_t)v * H);
            float acc = 0.f;
#pragma unroll
            for (int k = 0; k < 4; ++k) acc += dot4(wr[64 * k + lane], hreg[k]);
            acc = wred_sum(acc) + args.bo[v];
            if (lane == 0) args.out_logits[v] = acc;
            float M = fmaxf(m, acc);
            s = s * expf(m - M) + expf(acc - M);
            m = M;
        }
        if (lane == 0) { s_a[wv] = m; s_b[wv] = s; }
        __syncthreads();
        if (t == 0) {
            float M = s_a[0], S = s_b[0];
#pragma unroll
            for (int i = 1; i < 4; ++i) ms_merge(M, S, s_a[i], s_b[i]);
            args.pm[b] = M; args.ps[b] = S;
        }
    }
    gbar(args.bar, 4, nblk);

    // ---- P5: redundant (m,s) reduce -> C; coalesced grid-stride subtract ---
    {
        float m2 = -INFINITY, s2 = 0.f;
        for (int i = t; i < (int)nblk; i += 256) ms_merge(m2, s2, args.pm[i], args.ps[i]);
#pragma unroll
        for (int o = 32; o > 0; o >>= 1) {
            float mo = __shfl_xor(m2, o, 64), so = __shfl_xor(s2, o, 64);
            ms_merge(m2, s2, mo, so);
        }
        if (lane == 0) { s_a[wv] = m2; s_b[wv] = s2; }
        __syncthreads();
        if (t == 0) {
            float M = s_a[0], S = s_b[0];
#pragma unroll
            for (int i = 1; i < 4; ++i) ms_merge(M, S, s_a[i], s_b[i]);
            s_c = M + logf(S);
        }
        __syncthreads();
        const float C = s_c;
        for (int v = b * 256 + t; v < V; v += nblk * 256)
            args.out_logits[v] -= C;
    }
}

extern "C" void kernel_launch(void* const* d_in, const int* in_sizes, int n_in,
                              void* d_out, int out_size, void* d_ws, size_t ws_size,
                              hipStream_t stream) {
    Args a;
    a.tok = (const int*)d_in[0];
    a.hid = (const float*)d_in[1];
    a.enc = (const float*)d_in[2];
    a.emb = (const float*)d_in[3];
    a.Wa  = (const float*)d_in[4];
    a.ba  = (const float*)d_in[5];
    a.Wc  = (const float*)d_in[6];
    a.bcb = (const float*)d_in[7];
    a.Wih = (const float*)d_in[8];
    a.Whh = (const float*)d_in[9];
    a.bih = (const float*)d_in[10];
    a.bhh = (const float*)d_in[11];
    a.Wo  = (const float*)d_in[12];
    a.bo  = (const float*)d_in[13];

    float* out = (float*)d_out;       // [V | H | L]
    float* ws  = (float*)d_ws;
    a.elg = ws;                       // 512
    a.gh  = ws + 512;                 // 3072
    a.aa  = ws + 3584;                // 1024 (16B aligned)
    a.xv  = ws + 4608;                // 1024 (16B aligned)
    a.hn  = ws + 5632;                // 1024 (16B aligned)
    a.pm  = ws + 6656;                // 1024
    a.ps  = ws + 7680;                // 1024
    a.bar = (unsigned*)(ws + 8704);   // 5 phases x 16 stripes x 32 uints = 10KB
    a.out_logits = out;
    a.out_hnew   = out + V;
    a.out_attnw  = out + V + H;

    int occ = 0;
    hipOccupancyMaxActiveBlocksPerMultiprocessor(&occ, mega, 256, 0);
    if (occ < 1) occ = 1;
    unsigned nblk = (unsigned)occ * 256u;
    if (nblk > MAXNB) nblk = MAXNB;

    hipMemsetAsync(a.bar, 0, 5 * 512 * sizeof(unsigned), stream);
    mega<<<nblk, 256, 0, stream>>>(a);
}

// Round 5
// 64.609 us; speedup vs baseline: 2.7315x; 2.7315x over previous
//
#include <hip/hip_runtime.h>
#include <cmath>

#define H 1024
#define V 50257
#define L 512
#define NB5 1571   // ceil(V/32) blocks for the out-GEMV
#define NPART 128  // attn numerator partials

__device__ __forceinline__ float wred_sum(float v) {
#pragma unroll
    for (int o = 32; o > 0; o >>= 1) v += __shfl_xor(v, o, 64);
    return v;
}
__device__ __forceinline__ float dot4(float4 a, float4 b) {
    return a.x * b.x + a.y * b.y + a.z * b.z + a.w * b.w;
}
__device__ __forceinline__ void ms_merge(float& m, float& s, float m2, float s2) {
    float M = fmaxf(m, m2);
    if (M == -INFINITY) { m = M; s = 0.f; return; }
    s = s * expf(m - M) + s2 * expf(m2 - M);
    m = M;
}

// K1 (384 blocks):
//  blocks [0,128): wave wv computes elg[l]=exp(attn_logit l), l=b*4+wv (local!),
//                  then the block writes its 4-row weighted-enc partial to
//                  pbuf[b][0..1023] (unique owner — no atomics).
//  blocks [128,384): gh[j] = h . W_hh[j,:] + b_hh[j], 12 rows/block (3/wave).
__global__ void k_phase1(const int* __restrict__ tok,
                         const float* __restrict__ hid,
                         const float* __restrict__ emb,
                         const float* __restrict__ Wa,
                         const float* __restrict__ ba,
                         const float* __restrict__ enc,
                         const float* __restrict__ Whh,
                         const float* __restrict__ bhh,
                         float* __restrict__ elg,
                         float* __restrict__ pbuf,   // [128][1024]
                         float* __restrict__ gh) {
    const int t = threadIdx.x, lane = t & 63, wv = t >> 6, b = blockIdx.x;
    const float4* h4 = (const float4*)hid;
    if (b < NPART) {
        const int l = b * 4 + wv;
        const float4* e4 = (const float4*)(emb + (size_t)tok[0] * H);
        const float4* wr = (const float4*)(Wa + (size_t)l * 2048);
        float acc = 0.f;
#pragma unroll
        for (int k = 0; k < 8; ++k) {
            int f = 64 * k + lane;
            float4 s = (f < 256) ? e4[f] : h4[f - 256];
            acc += dot4(wr[f], s);
        }
        acc = wred_sum(acc);
        const float e = expf(acc + ba[l]);
        __shared__ float se[4];
        if (lane == 0) { se[wv] = e; elg[l] = e; }
        __syncthreads();
        float4 a = make_float4(0.f, 0.f, 0.f, 0.f);
#pragma unroll
        for (int r = 0; r < 4; ++r) {
            const float w = se[r];
            const float4 v = ((const float4*)(enc + (size_t)(b * 4 + r) * H))[t];
            a.x += w * v.x; a.y += w * v.y; a.z += w * v.z; a.w += w * v.w;
        }
        ((float4*)pbuf)[b * 256 + t] = a;
    } else {
        const int base = (b - NPART) * 12 + wv * 3;
#pragma unroll
        for (int r = 0; r < 3; ++r) {
            const int j = base + r;
            const float4* wh = (const float4*)(Whh + (size_t)j * H);
            float acc = 0.f;
#pragma unroll
            for (int k = 0; k < 4; ++k) {
                int f = 64 * k + lane;
                acc += dot4(wh[f], h4[f]);
            }
            acc = wred_sum(acc);
            if (lane == 0) gh[j] = acc + bhh[j];
        }
    }
}

// K2 (256 blocks): reduce 128 partials -> aa (LDS), invS from elg,
//  block 0 writes attn_weights, then x[j]=relu([emb,aa].Wc[j]+bc[j]) wave-per-row.
__global__ void k_comb(const int* __restrict__ tok,
                       const float* __restrict__ emb,
                       const float* __restrict__ elg,
                       const float* __restrict__ pbuf,
                       const float* __restrict__ Wc,
                       const float* __restrict__ bcb,
                       float* __restrict__ xv,
                       float* __restrict__ wout) {
    const int t = threadIdx.x, lane = t & 63, wv = t >> 6, b = blockIdx.x;
    __shared__ float red[4];
    __shared__ float4 aaL[256];
    const float e0 = elg[t], e1 = elg[t + 256];
    float s = wred_sum(e0 + e1);
    if (lane == 0) red[wv] = s;
    __syncthreads();
    const float invS = 1.f / (red[0] + red[1] + red[2] + red[3]);
    // reduce partials (L2-hot): thread t owns float4 column t
    float4 a = make_float4(0.f, 0.f, 0.f, 0.f);
#pragma unroll 8
    for (int i = 0; i < NPART; ++i) {
        const float4 p = ((const float4*)pbuf)[i * 256 + t];
        a.x += p.x; a.y += p.y; a.z += p.z; a.w += p.w;
    }
    a.x *= invS; a.y *= invS; a.z *= invS; a.w *= invS;
    aaL[t] = a;
    __syncthreads();
    if (b == 0) { wout[t] = e0 * invS; wout[t + 256] = e1 * invS; }
    const int j = b * 4 + wv;
    const float4* e4 = (const float4*)(emb + (size_t)tok[0] * H);
    const float4* wr = (const float4*)(Wc + (size_t)j * 2048);
    float acc = 0.f;
#pragma unroll
    for (int k = 0; k < 4; ++k) {
        int f = 64 * k + lane;
        acc += dot4(wr[f], e4[f]);
        acc += dot4(wr[256 + f], aaL[f]);
    }
    acc = wred_sum(acc);
    if (lane == 0) xv[j] = fmaxf(acc + bcb[j], 0.f);
}

// K3 (256 blocks): fused gates+GRU; wave per j.
__global__ void k_gates_gru(const float* __restrict__ xv,
                            const float* __restrict__ hid,
                            const float* __restrict__ Wih,
                            const float* __restrict__ bih,
                            const float* __restrict__ gh,
                            float* __restrict__ hn_out,
                            float* __restrict__ hn_ws) {
    const int lane = threadIdx.x & 63, wv = threadIdx.x >> 6;
    const int j = blockIdx.x * 4 + wv;
    const float4* x4 = (const float4*)xv;
    float4 xreg[4];
#pragma unroll
    for (int k = 0; k < 4; ++k) xreg[k] = x4[64 * k + lane];
    float g[3];
#pragma unroll
    for (int p = 0; p < 3; ++p) {
        const float4* wr = (const float4*)(Wih + (size_t)(j + p * H) * H);
        float acc = 0.f;
#pragma unroll
        for (int k = 0; k < 4; ++k) acc += dot4(wr[64 * k + lane], xreg[k]);
        g[p] = wred_sum(acc) + bih[j + p * H];
    }
    if (lane == 0) {
        float r = 1.f / (1.f + expf(-(g[0] + gh[j])));
        float z = 1.f / (1.f + expf(-(g[1] + gh[j + H])));
        float n = tanhf(g[2] + r * gh[j + 2 * H]);
        float hv = (1.f - z) * n + z * hid[j];
        hn_out[j] = hv;
        hn_ws[j] = hv;
    }
}

// K4 (1571 blocks): logits GEMV, wave-per-row x 8 rows, deferred wave-uniform
//  (max,sumexp) per block.
__global__ void k_out_gemv(const float* __restrict__ hn,
                           const float* __restrict__ Wo,
                           const float* __restrict__ bo,
                           float* __restrict__ logits,
                           float* __restrict__ pm,
                           float* __restrict__ ps) {
    const int lane = threadIdx.x & 63, wv = threadIdx.x >> 6;
    const int b = blockIdx.x;
    const float4* h4 = (const float4*)hn;
    float4 hreg[4];
#pragma unroll
    for (int k = 0; k < 4; ++k) hreg[k] = h4[64 * k + lane];
    float lv[8];
    int nvalid = 0;
#pragma unroll
    for (int i = 0; i < 8; ++i) {
        const int v = b * 32 + wv * 8 + i;
        if (v < V) {
            const float4* wr = (const float4*)(Wo + (size_t)v * H);
            float acc = 0.f;
#pragma unroll
            for (int k = 0; k < 4; ++k) acc += dot4(wr[64 * k + lane], hreg[k]);
            acc = wred_sum(acc) + bo[v];
            if (lane == 0) logits[v] = acc;
            lv[nvalid++] = acc;   // wave-uniform
        }
    }
    float m = -INFINITY, s = 0.f;
    for (int i = 0; i < nvalid; ++i) m = fmaxf(m, lv[i]);
    for (int i = 0; i < nvalid; ++i) s += expf(lv[i] - m);
    __shared__ float smm[4], sms[4];
    if (lane == 0) { smm[wv] = m; sms[wv] = s; }
    __syncthreads();
    if (threadIdx.x == 0) {
        float M = smm[0], S = sms[0];
#pragma unroll
        for (int i = 1; i < 4; ++i) ms_merge(M, S, smm[i], sms[i]);
        pm[b] = M; ps[b] = S;
    }
}

// K5 (197 blocks): redundant (m,s) reduce -> C; coalesced subtract.
__global__ void k_finalize(float* __restrict__ out,
                           const float* __restrict__ pm,
                           const float* __restrict__ ps) {
    const int t = threadIdx.x, lane = t & 63, wv = t >> 6;
    float m = -INFINITY, s = 0.f;
    for (int i = t; i < NB5; i += 256) ms_merge(m, s, pm[i], ps[i]);
#pragma unroll
    for (int o = 32; o > 0; o >>= 1) {
        float m2 = __shfl_xor(m, o, 64);
        float s2 = __shfl_xor(s, o, 64);
        ms_merge(m, s, m2, s2);
    }
    __shared__ float smm[4], sms[4];
    __shared__ float Cs;
    if (lane == 0) { smm[wv] = m; sms[wv] = s; }
    __syncthreads();
    if (t == 0) {
        float M = smm[0], S = sms[0];
#pragma unroll
        for (int i = 1; i < 4; ++i) ms_merge(M, S, smm[i], sms[i]);
        Cs = M + logf(S);
    }
    __syncthreads();
    const float C = Cs;
    const int v = blockIdx.x * 256 + t;
    if (v < V) out[v] -= C;
}

extern "C" void kernel_launch(void* const* d_in, const int* in_sizes, int n_in,
                              void* d_out, int out_size, void* d_ws, size_t ws_size,
                              hipStream_t stream) {
    const int*   tok = (const int*)d_in[0];
    const float* hid = (const float*)d_in[1];
    const float* enc = (const float*)d_in[2];
    const float* emb = (const float*)d_in[3];
    const float* Wa  = (const float*)d_in[4];
    const float* ba  = (const float*)d_in[5];
    const float* Wc  = (const float*)d_in[6];
    const float* bc  = (const float*)d_in[7];
    const float* Wih = (const float*)d_in[8];
    const float* Whh = (const float*)d_in[9];
    const float* bih = (const float*)d_in[10];
    const float* bhh = (const float*)d_in[11];
    const float* Wo  = (const float*)d_in[12];
    const float* bo  = (const float*)d_in[13];

    float* out = (float*)d_out;   // [V | H | L]
    float* ws  = (float*)d_ws;
    float* elg  = ws;                 // 512
    float* gh   = ws + 512;           // 3072
    float* xv   = ws + 3584;          // 1024 (16B aligned)
    float* hn   = ws + 4608;          // 1024 (16B aligned)
    float* pm   = ws + 5632;          // 1571
    float* psum = ws + 7203;          // 1571
    float* pbuf = ws + 8832;          // 128*1024 (16B aligned)

    float* out_logits = out;          // V
    float* out_hnew   = out + V;      // H
    float* out_attnw  = out + V + H;  // L

    k_phase1<<<384, 256, 0, stream>>>(tok, hid, emb, Wa, ba, enc, Whh, bhh,
                                      elg, pbuf, gh);
    k_comb<<<256, 256, 0, stream>>>(tok, emb, elg, pbuf, Wc, bc, xv, out_attnw);
    k_gates_gru<<<256, 256, 0, stream>>>(xv, hid, Wih, bih, gh, out_hnew, hn);
    k_out_gemv<<<NB5, 256, 0, stream>>>(hn, Wo, bo, out_logits, pm, psum);
    k_finalize<<<197, 256, 0, stream>>>(out_logits, pm, psum);
}

// Round 6
// 61.745 us; speedup vs baseline: 2.8582x; 1.0464x over previous
//
#include <hip/hip_runtime.h>
#include <cmath>

#define H 1024
#define V 50257
#define L 512
#define NB5 1571   // ceil(V/32) blocks for the out-GEMV
#define NPART 32   // attn numerator partials (32 x 4KB = 128KB redundant read/block in comb)

__device__ __forceinline__ float wred_sum(float v) {
#pragma unroll
    for (int o = 32; o > 0; o >>= 1) v += __shfl_xor(v, o, 64);
    return v;
}
__device__ __forceinline__ float dot4(float4 a, float4 b) {
    return a.x * b.x + a.y * b.y + a.z * b.z + a.w * b.w;
}
__device__ __forceinline__ void ms_merge(float& m, float& s, float m2, float s2) {
    float M = fmaxf(m, m2);
    if (M == -INFINITY) { m = M; s = 0.f; return; }
    s = s * expf(m - M) + s2 * expf(m2 - M);
    m = M;
}

// K1 (800 blocks):
//  blocks [0,32):  16 attn rows each: wave wv computes elg for rows b*16+wv*4+{0..3},
//                  then block-wide weighted-enc partial -> pbuf[b][1024] (unique owner).
//  blocks [32,800): gh[j] = h . W_hh[j,:] + b_hh[j], wave-per-row (4 rows/block).
__global__ void k_phase1(const int* __restrict__ tok,
                         const float* __restrict__ hid,
                         const float* __restrict__ emb,
                         const float* __restrict__ Wa,
                         const float* __restrict__ ba,
                         const float* __restrict__ enc,
                         const float* __restrict__ Whh,
                         const float* __restrict__ bhh,
                         float* __restrict__ elg,
                         float* __restrict__ pbuf,   // [32][1024]
                         float* __restrict__ gh) {
    const int t = threadIdx.x, lane = t & 63, wv = t >> 6, b = blockIdx.x;
    const float4* h4 = (const float4*)hid;
    if (b < NPART) {
        const int rbase = b * 16;
        const float4* e4 = (const float4*)(emb + (size_t)tok[0] * H);
        __shared__ float se[16];
#pragma unroll
        for (int r = 0; r < 4; ++r) {
            const int l = rbase + wv * 4 + r;
            const float4* wr = (const float4*)(Wa + (size_t)l * 2048);
            float acc = 0.f;
#pragma unroll
            for (int k = 0; k < 8; ++k) {
                int f = 64 * k + lane;
                float4 s = (f < 256) ? e4[f] : h4[f - 256];
                acc += dot4(wr[f], s);
            }
            acc = wred_sum(acc);
            if (lane == 0) {
                const float e = expf(acc + ba[l]);
                se[wv * 4 + r] = e;
                elg[l] = e;
            }
        }
        __syncthreads();
        float4 a = make_float4(0.f, 0.f, 0.f, 0.f);
#pragma unroll
        for (int r = 0; r < 16; ++r) {
            const float w = se[r];
            const float4 v = ((const float4*)(enc + (size_t)(rbase + r) * H))[t];
            a.x += w * v.x; a.y += w * v.y; a.z += w * v.z; a.w += w * v.w;
        }
        ((float4*)pbuf)[b * 256 + t] = a;
    } else {
        const int j = (b - NPART) * 4 + wv;   // [0, 3072)
        const float4* wh = (const float4*)(Whh + (size_t)j * H);
        float acc = 0.f;
#pragma unroll
        for (int k = 0; k < 4; ++k) {
            int f = 64 * k + lane;
            acc += dot4(wh[f], h4[f]);
        }
        acc = wred_sum(acc);
        if (lane == 0) gh[j] = acc + bhh[j];
    }
}

// K2 (256 blocks): invS from elg, reduce 32 partials -> aa (LDS), block 0 writes
//  attn_weights, then x[j] = relu([emb, aa] . Wc[j,:] + bc[j]) wave-per-row.
__global__ void k_comb(const int* __restrict__ tok,
                       const float* __restrict__ emb,
                       const float* __restrict__ elg,
                       const float* __restrict__ pbuf,
                       const float* __restrict__ Wc,
                       const float* __restrict__ bcb,
                       float* __restrict__ xv,
                       float* __restrict__ wout) {
    const int t = threadIdx.x, lane = t & 63, wv = t >> 6, b = blockIdx.x;
    __shared__ float red[4];
    __shared__ float4 aaL[256];
    const float e0 = elg[t], e1 = elg[t + 256];
    float s = wred_sum(e0 + e1);
    if (lane == 0) red[wv] = s;
    __syncthreads();
    const float invS = 1.f / (red[0] + red[1] + red[2] + red[3]);
    float4 a = make_float4(0.f, 0.f, 0.f, 0.f);
#pragma unroll 8
    for (int i = 0; i < NPART; ++i) {
        const float4 p = ((const float4*)pbuf)[i * 256 + t];
        a.x += p.x; a.y += p.y; a.z += p.z; a.w += p.w;
    }
    a.x *= invS; a.y *= invS; a.z *= invS; a.w *= invS;
    aaL[t] = a;
    __syncthreads();
    if (b == 0) { wout[t] = e0 * invS; wout[t + 256] = e1 * invS; }
    const int j = b * 4 + wv;
    const float4* e4 = (const float4*)(emb + (size_t)tok[0] * H);
    const float4* wr = (const float4*)(Wc + (size_t)j * 2048);
    float acc = 0.f;
#pragma unroll
    for (int k = 0; k < 4; ++k) {
        int f = 64 * k + lane;
        acc += dot4(wr[f], e4[f]);
        acc += dot4(wr[256 + f], aaL[f]);
    }
    acc = wred_sum(acc);
    if (lane == 0) xv[j] = fmaxf(acc + bcb[j], 0.f);
}

// K3 (256 blocks): fused gates+GRU; wave per j.
__global__ void k_gates_gru(const float* __restrict__ xv,
                            const float* __restrict__ hid,
                            const float* __restrict__ Wih,
                            const float* __restrict__ bih,
                            const float* __restrict__ gh,
                            float* __restrict__ hn_out,
                            float* __restrict__ hn_ws) {
    const int lane = threadIdx.x & 63, wv = threadIdx.x >> 6;
    const int j = blockIdx.x * 4 + wv;
    const float4* x4 = (const float4*)xv;
    float4 xreg[4];
#pragma unroll
    for (int k = 0; k < 4; ++k) xreg[k] = x4[64 * k + lane];
    float g[3];
#pragma unroll
    for (int p = 0; p < 3; ++p) {
        const float4* wr = (const float4*)(Wih + (size_t)(j + p * H) * H);
        float acc = 0.f;
#pragma unroll
        for (int k = 0; k < 4; ++k) acc += dot4(wr[64 * k + lane], xreg[k]);
        g[p] = wred_sum(acc) + bih[j + p * H];
    }
    if (lane == 0) {
        float r = 1.f / (1.f + expf(-(g[0] + gh[j])));
        float z = 1.f / (1.f + expf(-(g[1] + gh[j + H])));
        float n = tanhf(g[2] + r * gh[j + 2 * H]);
        float hv = (1.f - z) * n + z * hid[j];
        hn_out[j] = hv;
        hn_ws[j] = hv;
    }
}

// K4 (1571 blocks): logits GEMV, wave-per-row x 8 rows, deferred wave-uniform
//  (max,sumexp) per block.
__global__ void k_out_gemv(const float* __restrict__ hn,
                           const float* __restrict__ Wo,
                           const float* __restrict__ bo,
                           float* __restrict__ logits,
                           float* __restrict__ pm,
                           float* __restrict__ ps) {
    const int lane = threadIdx.x & 63, wv = threadIdx.x >> 6;
    const int b = blockIdx.x;
    const float4* h4 = (const float4*)hn;
    float4 hreg[4];
#pragma unroll
    for (int k = 0; k < 4; ++k) hreg[k] = h4[64 * k + lane];
    float lv[8];
    int nvalid = 0;
#pragma unroll
    for (int i = 0; i < 8; ++i) {
        const int v = b * 32 + wv * 8 + i;
        if (v < V) {
            const float4* wr = (const float4*)(Wo + (size_t)v * H);
            float acc = 0.f;
#pragma unroll
            for (int k = 0; k < 4; ++k) acc += dot4(wr[64 * k + lane], hreg[k]);
            acc = wred_sum(acc) + bo[v];
            if (lane == 0) logits[v] = acc;
            lv[nvalid++] = acc;   // wave-uniform
        }
    }
    float m = -INFINITY, s = 0.f;
    for (int i = 0; i < nvalid; ++i) m = fmaxf(m, lv[i]);
    for (int i = 0; i < nvalid; ++i) s += expf(lv[i] - m);
    __shared__ float smm[4], sms[4];
    if (lane == 0) { smm[wv] = m; sms[wv] = s; }
    __syncthreads();
    if (threadIdx.x == 0) {
        float M = smm[0], S = sms[0];
#pragma unroll
        for (int i = 1; i < 4; ++i) ms_merge(M, S, smm[i], sms[i]);
        pm[b] = M; ps[b] = S;
    }
}

// K5 (197 blocks): redundant (m,s) reduce -> C; coalesced subtract.
__global__ void k_finalize(float* __restrict__ out,
                           const float* __restrict__ pm,
                           const float* __restrict__ ps) {
    const int t = threadIdx.x, lane = t & 63, wv = t >> 6;
    float m = -INFINITY, s = 0.f;
    for (int i = t; i < NB5; i += 256) ms_merge(m, s, pm[i], ps[i]);
#pragma unroll
    for (int o = 32; o > 0; o >>= 1) {
        float m2 = __shfl_xor(m, o, 64);
        float s2 = __shfl_xor(s, o, 64);
        ms_merge(m, s, m2, s2);
    }
    __shared__ float smm[4], sms[4];
    __shared__ float Cs;
    if (lane == 0) { smm[wv] = m; sms[wv] = s; }
    __syncthreads();
    if (t == 0) {
        float M = smm[0], S = sms[0];
#pragma unroll
        for (int i = 1; i < 4; ++i) ms_merge(M, S, smm[i], sms[i]);
        Cs = M + logf(S);
    }
    __syncthreads();
    const float C = Cs;
    const int v = blockIdx.x * 256 + t;
    if (v < V) out[v] -= C;
}

extern "C" void kernel_launch(void* const* d_in, const int* in_sizes, int n_in,
                              void* d_out, int out_size, void* d_ws, size_t ws_size,
                              hipStream_t stream) {
    const int*   tok = (const int*)d_in[0];
    const float* hid = (const float*)d_in[1];
    const float* enc = (const float*)d_in[2];
    const float* emb = (const float*)d_in[3];
    const float* Wa  = (const float*)d_in[4];
    const float* ba  = (const float*)d_in[5];
    const float* Wc  = (const float*)d_in[6];
    const float* bc  = (const float*)d_in[7];
    const float* Wih = (const float*)d_in[8];
    const float* Whh = (const float*)d_in[9];
    const float* bih = (const float*)d_in[10];
    const float* bhh = (const float*)d_in[11];
    const float* Wo  = (const float*)d_in[12];
    const float* bo  = (const float*)d_in[13];

    float* out = (float*)d_out;   // [V | H | L]
    float* ws  = (float*)d_ws;
    float* elg  = ws;                 // 512
    float* gh   = ws + 512;           // 3072
    float* xv   = ws + 3584;          // 1024 (16B aligned)
    float* hn   = ws + 4608;          // 1024 (16B aligned)
    float* pm   = ws + 5632;          // 1571
    float* psum = ws + 7203;          // 1571
    float* pbuf = ws + 8832;          // 32*1024 (16B aligned)

    float* out_logits = out;          // V
    float* out_hnew   = out + V;      // H
    float* out_attnw  = out + V + H;  // L

    k_phase1<<<NPART + 768, 256, 0, stream>>>(tok, hid, emb, Wa, ba, enc, Whh, bhh,
                                              elg, pbuf, gh);
    k_comb<<<256, 256, 0, stream>>>(tok, emb, elg, pbuf, Wc, bc, xv, out_attnw);
    k_gates_gru<<<256, 256, 0, stream>>>(xv, hid, Wih, bih, gh, out_hnew, hn);
    k_out_gemv<<<NB5, 256, 0, stream>>>(hn, Wo, bo, out_logits, pm, psum);
    k_finalize<<<197, 256, 0, stream>>>(out_logits, pm, psum);
}

// Round 7
// 61.274 us; speedup vs baseline: 2.8802x; 1.0077x over previous
//
#include <hip/hip_runtime.h>
#include <cmath>

#define H 1024
#define V 50257
#define L 512
#define NB5 1571   // ceil(V/32) blocks for the out-GEMV
#define NPART 128  // attn numerator partials (4 rows each)

typedef float f4 __attribute__((ext_vector_type(4)));

__device__ __forceinline__ float wred_sum(float v) {
#pragma unroll
    for (int o = 32; o > 0; o >>= 1) v += __shfl_xor(v, o, 64);
    return v;
}
__device__ __forceinline__ float dot4f(f4 a, f4 b) {
    return a.x * b.x + a.y * b.y + a.z * b.z + a.w * b.w;
}
__device__ __forceinline__ void ms_merge(float& m, float& s, float m2, float s2) {
    float M = fmaxf(m, m2);
    if (M == -INFINITY) { m = M; s = 0.f; return; }
    s = s * expf(m - M) + s2 * expf(m2 - M);
    m = M;
}

// K1 (896 blocks):
//  blocks [0,128):  4 attn rows (wave-per-row): elg[l]=exp(logit_l), then block
//                   writes its 4-row weighted-enc partial to pbuf[b] (unique owner).
//  blocks [128,896): gh[j] = h . W_hh[j,:] + b_hh[j], wave-per-row (4 rows/block).
__global__ void k_phase1(const int* __restrict__ tok,
                         const float* __restrict__ hid,
                         const float* __restrict__ emb,
                         const float* __restrict__ Wa,
                         const float* __restrict__ ba,
                         const float* __restrict__ enc,
                         const float* __restrict__ Whh,
                         const float* __restrict__ bhh,
                         float* __restrict__ elg,
                         float* __restrict__ pbuf,   // [128][1024]
                         float* __restrict__ gh) {
    const int t = threadIdx.x, lane = t & 63, wv = t >> 6, b = blockIdx.x;
    const f4* h4 = (const f4*)hid;
    if (b < NPART) {
        const int l = b * 4 + wv;
        const f4* e4 = (const f4*)(emb + (size_t)tok[0] * H);
        const f4* wr = (const f4*)(Wa + (size_t)l * 2048);
        float acc = 0.f;
#pragma unroll
        for (int k = 0; k < 8; ++k) {
            int f = 64 * k + lane;
            f4 s = (f < 256) ? e4[f] : h4[f - 256];
            acc += dot4f(wr[f], s);
        }
        acc = wred_sum(acc);
        __shared__ float se[4];
        const float e = expf(acc + ba[l]);
        if (lane == 0) { se[wv] = e; elg[l] = e; }
        __syncthreads();
        f4 a = {0.f, 0.f, 0.f, 0.f};
#pragma unroll
        for (int r = 0; r < 4; ++r)
            a += se[r] * ((const f4*)(enc + (size_t)(b * 4 + r) * H))[t];
        ((f4*)pbuf)[b * 256 + t] = a;
    } else {
        const int j = (b - NPART) * 4 + wv;   // [0, 3072)
        const f4* wh = (const f4*)(Whh + (size_t)j * H);
        float acc = 0.f;
#pragma unroll
        for (int k = 0; k < 4; ++k) {
            int f = 64 * k + lane;
            acc += dot4f(wh[f], h4[f]);
        }
        acc = wred_sum(acc);
        if (lane == 0) gh[j] = acc + bhh[j];
    }
}

// K2 (4 blocks): deterministic reduce of 128 partials -> aa (invS-scaled);
//  block b owns f4 columns [b*64, b*64+64), 4 threads per column.
//  Block 0 also writes attn_weights.
__global__ void k_reduce(const float* __restrict__ elg,
                         const float* __restrict__ pbuf,
                         float* __restrict__ aa,
                         float* __restrict__ wout) {
    const int t = threadIdx.x, b = blockIdx.x;
    const int g = t >> 6, c = t & 63;
    __shared__ float red[4];
    const float e0 = elg[t], e1 = elg[t + 256];
    float s = wred_sum(e0 + e1);
    if (c == 0) red[g] = s;
    __syncthreads();
    const float invS = 1.f / (red[0] + red[1] + red[2] + red[3]);
    const int col = b * 64 + c;          // f4 column in [0,256)
    f4 a = {0.f, 0.f, 0.f, 0.f};
#pragma unroll 8
    for (int i = g; i < NPART; i += 4) a += ((const f4*)pbuf)[i * 256 + col];
    __shared__ f4 racc[4][64];
    racc[g][c] = a;
    __syncthreads();
    if (g == 0) {
        f4 tot = (racc[0][c] + racc[1][c] + racc[2][c] + racc[3][c]) * invS;
        ((f4*)aa)[col] = tot;
    }
    if (b == 0) { wout[t] = e0 * invS; wout[t + 256] = e1 * invS; }
}

// K3 (256 blocks): x[j] = relu([emb, aa] . Wc[j,:] + bc[j]); wave-per-row.
__global__ void k_comb(const int* __restrict__ tok,
                       const float* __restrict__ emb,
                       const float* __restrict__ aa,
                       const float* __restrict__ Wc,
                       const float* __restrict__ bcb,
                       float* __restrict__ xv) {
    const int lane = threadIdx.x & 63, wv = threadIdx.x >> 6;
    const int j = blockIdx.x * 4 + wv;
    const f4* e4 = (const f4*)(emb + (size_t)tok[0] * H);
    const f4* a4 = (const f4*)aa;
    const f4* wr = (const f4*)(Wc + (size_t)j * 2048);
    float acc = 0.f;
#pragma unroll
    for (int k = 0; k < 4; ++k) {
        int f = 64 * k + lane;
        acc += dot4f(wr[f], e4[f]);
        acc += dot4f(wr[256 + f], a4[f]);
    }
    acc = wred_sum(acc);
    if (lane == 0) xv[j] = fmaxf(acc + bcb[j], 0.f);
}

// K4 (256 blocks): fused gates+GRU; wave per j.
__global__ void k_gates_gru(const float* __restrict__ xv,
                            const float* __restrict__ hid,
                            const float* __restrict__ Wih,
                            const float* __restrict__ bih,
                            const float* __restrict__ gh,
                            float* __restrict__ hn_out,
                            float* __restrict__ hn_ws) {
    const int lane = threadIdx.x & 63, wv = threadIdx.x >> 6;
    const int j = blockIdx.x * 4 + wv;
    const f4* x4 = (const f4*)xv;
    f4 xreg[4];
#pragma unroll
    for (int k = 0; k < 4; ++k) xreg[k] = x4[64 * k + lane];
    float g[3];
#pragma unroll
    for (int p = 0; p < 3; ++p) {
        const f4* wr = (const f4*)(Wih + (size_t)(j + p * H) * H);
        float acc = 0.f;
#pragma unroll
        for (int k = 0; k < 4; ++k) acc += dot4f(wr[64 * k + lane], xreg[k]);
        g[p] = wred_sum(acc) + bih[j + p * H];
    }
    if (lane == 0) {
        float r = 1.f / (1.f + expf(-(g[0] + gh[j])));
        float z = 1.f / (1.f + expf(-(g[1] + gh[j + H])));
        float n = tanhf(g[2] + r * gh[j + 2 * H]);
        float hv = (1.f - z) * n + z * hid[j];
        hn_out[j] = hv;
        hn_ws[j] = hv;
    }
}

// K5 (1571 blocks): logits GEMV, wave-per-row x 8 rows; bounds-check-free fast
//  path for all but the last block; nontemporal loads for the streamed W_out.
__global__ void k_out_gemv(const float* __restrict__ hn,
                           const float* __restrict__ Wo,
                           const float* __restrict__ bo,
                           float* __restrict__ logits,
                           float* __restrict__ pm,
                           float* __restrict__ ps) {
    const int lane = threadIdx.x & 63, wv = threadIdx.x >> 6;
    const int b = blockIdx.x;
    const int rbase = b * 32 + wv * 8;
    const f4* h4 = (const f4*)hn;
    f4 hreg[4];
#pragma unroll
    for (int k = 0; k < 4; ++k) hreg[k] = h4[64 * k + lane];
    float m = -INFINITY, s = 0.f;
    if (b != NB5 - 1) {
        float lv[8];
#pragma unroll
        for (int i = 0; i < 8; ++i) {
            const f4* wr = (const f4*)(Wo + (size_t)(rbase + i) * H);
            float acc = 0.f;
#pragma unroll
            for (int k = 0; k < 4; ++k)
                acc += dot4f(__builtin_nontemporal_load(wr + 64 * k + lane), hreg[k]);
            acc = wred_sum(acc) + bo[rbase + i];
            if (lane == 0) logits[rbase + i] = acc;
            lv[i] = acc;
        }
#pragma unroll
        for (int i = 0; i < 8; ++i) m = fmaxf(m, lv[i]);
#pragma unroll
        for (int i = 0; i < 8; ++i) s += expf(lv[i] - m);
    } else {
#pragma unroll
        for (int i = 0; i < 8; ++i) {
            const int v = rbase + i;
            if (v < V) {
                const f4* wr = (const f4*)(Wo + (size_t)v * H);
                float acc = 0.f;
#pragma unroll
                for (int k = 0; k < 4; ++k)
                    acc += dot4f(__builtin_nontemporal_load(wr + 64 * k + lane), hreg[k]);
                acc = wred_sum(acc) + bo[v];
                if (lane == 0) logits[v] = acc;
                float M = fmaxf(m, acc);
                s = s * expf(m - M) + expf(acc - M);
                m = M;
            }
        }
    }
    __shared__ float smm[4], sms[4];
    if (lane == 0) { smm[wv] = m; sms[wv] = s; }
    __syncthreads();
    if (threadIdx.x == 0) {
        float M = smm[0], S = sms[0];
#pragma unroll
        for (int i = 1; i < 4; ++i) ms_merge(M, S, smm[i], sms[i]);
        pm[b] = M; ps[b] = S;
    }
}

// K6 (197 blocks): redundant (m,s) reduce -> C; coalesced subtract.
__global__ void k_finalize(float* __restrict__ out,
                           const float* __restrict__ pm,
                           const float* __restrict__ ps) {
    const int t = threadIdx.x, lane = t & 63, wv = t >> 6;
    float m = -INFINITY, s = 0.f;
    for (int i = t; i < NB5; i += 256) ms_merge(m, s, pm[i], ps[i]);
#pragma unroll
    for (int o = 32; o > 0; o >>= 1) {
        float m2 = __shfl_xor(m, o, 64);
        float s2 = __shfl_xor(s, o, 64);
        ms_merge(m, s, m2, s2);
    }
    __shared__ float smm[4], sms[4];
    __shared__ float Cs;
    if (lane == 0) { smm[wv] = m; sms[wv] = s; }
    __syncthreads();
    if (t == 0) {
        float M = smm[0], S = sms[0];
#pragma unroll
        for (int i = 1; i < 4; ++i) ms_merge(M, S, smm[i], sms[i]);
        Cs = M + logf(S);
    }
    __syncthreads();
    const float C = Cs;
    const int v = blockIdx.x * 256 + t;
    if (v < V) out[v] -= C;
}

extern "C" void kernel_launch(void* const* d_in, const int* in_sizes, int n_in,
                              void* d_out, int out_size, void* d_ws, size_t ws_size,
                              hipStream_t stream) {
    const int*   tok = (const int*)d_in[0];
    const float* hid = (const float*)d_in[1];
    const float* enc = (const float*)d_in[2];
    const float* emb = (const float*)d_in[3];
    const float* Wa  = (const float*)d_in[4];
    const float* ba  = (const float*)d_in[5];
    const float* Wc  = (const float*)d_in[6];
    const float* bc  = (const float*)d_in[7];
    const float* Wih = (const float*)d_in[8];
    const float* Whh = (const float*)d_in[9];
    const float* bih = (const float*)d_in[10];
    const float* bhh = (const float*)d_in[11];
    const float* Wo  = (const float*)d_in[12];
    const float* bo  = (const float*)d_in[13];

    float* out = (float*)d_out;   // [V | H | L]
    float* ws  = (float*)d_ws;
    float* elg  = ws;                 // 512
    float* gh   = ws + 512;           // 3072
    float* aa   = ws + 3584;          // 1024 (16B aligned)
    float* xv   = ws + 4608;          // 1024 (16B aligned)
    float* hn   = ws + 5632;          // 1024 (16B aligned)
    float* pm   = ws + 6656;          // 1600
    float* psum = ws + 8256;          // 1600
    float* pbuf = ws + 9856;          // 128*1024 (16B aligned)

    float* out_logits = out;          // V
    float* out_hnew   = out + V;      // H
    float* out_attnw  = out + V + H;  // L

    k_phase1<<<NPART + 768, 256, 0, stream>>>(tok, hid, emb, Wa, ba, enc, Whh, bhh,
                                              elg, pbuf, gh);
    k_reduce<<<4, 256, 0, stream>>>(elg, pbuf, aa, out_attnw);
    k_comb<<<256, 256, 0, stream>>>(tok, emb, aa, Wc, bc, xv);
    k_gates_gru<<<256, 256, 0, stream>>>(xv, hid, Wih, bih, gh, out_hnew, hn);
    k_out_gemv<<<NB5, 256, 0, stream>>>(hn, Wo, bo, out_logits, pm, psum);
    k_finalize<<<197, 256, 0, stream>>>(out_logits, pm, psum);
}

// Round 8
// 55.708 us; speedup vs baseline: 3.1680x; 1.0999x over previous
//
#include <hip/hip_runtime.h>
#include <cmath>

#define H 1024
#define V 50257
#define L 512
#define NBGEMV 1024   // grid-stride GEMV blocks (exactly 4/CU)
#define NPART 256     // attn numerator partials (2 rows each)

typedef float f4 __attribute__((ext_vector_type(4)));

__device__ __forceinline__ float wred_sum(float v) {
#pragma unroll
    for (int o = 32; o > 0; o >>= 1) v += __shfl_xor(v, o, 64);
    return v;
}
__device__ __forceinline__ float dot4f(f4 a, f4 b) {
    return a.x * b.x + a.y * b.y + a.z * b.z + a.w * b.w;
}
__device__ __forceinline__ void ms_merge(float& m, float& s, float m2, float s2) {
    float M = fmaxf(m, m2);
    if (M == -INFINITY) { m = M; s = 0.f; return; }
    s = s * expf(m - M) + s2 * expf(m2 - M);
    m = M;
}

// K1 (1024 blocks, exactly 4/CU, ~uniform 16-24KB per block):
//  blocks [0,256):  2 attn rows; wave wv handles (row = 2b+(wv>>1), k-half = wv&1);
//                   exp-logits -> elg, then 2-row weighted-enc partial -> pbuf[b].
//  blocks [256,1024): gh[j] = h . W_hh[j,:] + b_hh[j], wave-per-row.
__global__ void k_phase1(const int* __restrict__ tok,
                         const float* __restrict__ hid,
                         const float* __restrict__ emb,
                         const float* __restrict__ Wa,
                         const float* __restrict__ ba,
                         const float* __restrict__ enc,
                         const float* __restrict__ Whh,
                         const float* __restrict__ bhh,
                         float* __restrict__ elg,
                         float* __restrict__ pbuf,   // [256][1024]
                         float* __restrict__ gh) {
    const int t = threadIdx.x, lane = t & 63, wv = t >> 6, b = blockIdx.x;
    const f4* h4 = (const f4*)hid;
    if (b < NPART) {
        const int row = 2 * b + (wv >> 1);
        const int half = wv & 1;
        const f4* e4 = (const f4*)(emb + (size_t)tok[0] * H);
        const f4* wr = (const f4*)(Wa + (size_t)row * 2048);
        float acc = 0.f;
#pragma unroll
        for (int k = 0; k < 4; ++k) {
            int f = half * 256 + 64 * k + lane;    // [0, 512)
            f4 s = (f < 256) ? e4[f] : h4[f - 256];
            acc += dot4f(wr[f], s);
        }
        acc = wred_sum(acc);
        __shared__ float sp[4];
        __shared__ float se[2];
        if (lane == 0) sp[wv] = acc;
        __syncthreads();
        if (t == 0) {
            float E0 = expf(sp[0] + sp[1] + ba[2 * b]);
            float E1 = expf(sp[2] + sp[3] + ba[2 * b + 1]);
            se[0] = E0; se[1] = E1;
            elg[2 * b] = E0; elg[2 * b + 1] = E1;
        }
        __syncthreads();
        f4 a = se[0] * ((const f4*)(enc + (size_t)(2 * b) * H))[t]
             + se[1] * ((const f4*)(enc + (size_t)(2 * b + 1) * H))[t];
        ((f4*)pbuf)[b * 256 + t] = a;
    } else {
        const int j = (b - NPART) * 4 + wv;   // [0, 3072)
        const f4* wh = (const f4*)(Whh + (size_t)j * H);
        float acc = 0.f;
#pragma unroll
        for (int k = 0; k < 4; ++k) {
            int f = 64 * k + lane;
            acc += dot4f(wh[f], h4[f]);
        }
        acc = wred_sum(acc);
        if (lane == 0) gh[j] = acc + bhh[j];
    }
}

// K2 (16 blocks): deterministic reduce of 256 partials -> aa (invS-scaled).
//  Block b owns f4-columns [16b, 16b+16); thread (g=t>>4, c=t&15) sums 16 stripes.
//  Block 0 also writes attn_weights.
__global__ void k_reduce(const float* __restrict__ elg,
                         const float* __restrict__ pbuf,
                         float* __restrict__ aa,
                         float* __restrict__ wout) {
    const int t = threadIdx.x, b = blockIdx.x;
    const int g = t >> 4, c = t & 15;
    __shared__ float red[4];
    const float e0 = elg[t], e1 = elg[t + 256];
    float s = wred_sum(e0 + e1);
    if ((t & 63) == 0) red[t >> 6] = s;
    __syncthreads();
    const float invS = 1.f / (red[0] + red[1] + red[2] + red[3]);
    const int col = b * 16 + c;
    f4 a = {0.f, 0.f, 0.f, 0.f};
#pragma unroll
    for (int i = 0; i < 16; ++i)
        a += ((const f4*)pbuf)[(size_t)(g + 16 * i) * 256 + col];
    __shared__ f4 racc[16][16];
    racc[g][c] = a;
    __syncthreads();
    if (g == 0) {
        f4 tot = {0.f, 0.f, 0.f, 0.f};
#pragma unroll
        for (int i = 0; i < 16; ++i) tot += racc[i][c];
        ((f4*)aa)[col] = tot * invS;
    }
    if (b == 0) { wout[t] = e0 * invS; wout[t + 256] = e1 * invS; }
}

// K3 (256 blocks): x[j] = relu([emb, aa] . Wc[j,:] + bc[j]); wave-per-row.
__global__ void k_comb(const int* __restrict__ tok,
                       const float* __restrict__ emb,
                       const float* __restrict__ aa,
                       const float* __restrict__ Wc,
                       const float* __restrict__ bcb,
                       float* __restrict__ xv) {
    const int lane = threadIdx.x & 63, wv = threadIdx.x >> 6;
    const int j = blockIdx.x * 4 + wv;
    const f4* e4 = (const f4*)(emb + (size_t)tok[0] * H);
    const f4* a4 = (const f4*)aa;
    const f4* wr = (const f4*)(Wc + (size_t)j * 2048);
    float acc = 0.f;
#pragma unroll
    for (int k = 0; k < 4; ++k) {
        int f = 64 * k + lane;
        acc += dot4f(wr[f], e4[f]);
        acc += dot4f(wr[256 + f], a4[f]);
    }
    acc = wred_sum(acc);
    if (lane == 0) xv[j] = fmaxf(acc + bcb[j], 0.f);
}

// K4 (256 blocks): fused gates+GRU; wave per j.
__global__ void k_gates_gru(const float* __restrict__ xv,
                            const float* __restrict__ hid,
                            const float* __restrict__ Wih,
                            const float* __restrict__ bih,
                            const float* __restrict__ gh,
                            float* __restrict__ hn_out,
                            float* __restrict__ hn_ws) {
    const int lane = threadIdx.x & 63, wv = threadIdx.x >> 6;
    const int j = blockIdx.x * 4 + wv;
    const f4* x4 = (const f4*)xv;
    f4 xreg[4];
#pragma unroll
    for (int k = 0; k < 4; ++k) xreg[k] = x4[64 * k + lane];
    float g[3];
#pragma unroll
    for (int p = 0; p < 3; ++p) {
        const f4* wr = (const f4*)(Wih + (size_t)(j + p * H) * H);
        float acc = 0.f;
#pragma unroll
        for (int k = 0; k < 4; ++k) acc += dot4f(wr[64 * k + lane], xreg[k]);
        g[p] = wred_sum(acc) + bih[j + p * H];
    }
    if (lane == 0) {
        float r = 1.f / (1.f + expf(-(g[0] + gh[j])));
        float z = 1.f / (1.f + expf(-(g[1] + gh[j + H])));
        float n = tanhf(g[2] + r * gh[j + 2 * H]);
        float hv = (1.f - z) * n + z * hid[j];
        hn_out[j] = hv;
        hn_ws[j] = hv;
    }
}

// K5 (1024 blocks, exactly 4/CU): grid-stride GEMV. Wave gw handles rows
//  gw, gw+4096, ... — all CUs sweep W_out in address order, imbalance <= 1 row.
//  Online (m,s) per wave, merged per block.
__global__ void k_out_gemv(const float* __restrict__ hn,
                           const float* __restrict__ Wo,
                           const float* __restrict__ bo,
                           float* __restrict__ logits,
                           float* __restrict__ pm,
                           float* __restrict__ ps) {
    const int lane = threadIdx.x & 63, wv = threadIdx.x >> 6;
    const int b = blockIdx.x;
    const int gw = b * 4 + wv;            // [0, 4096)
    const f4* h4 = (const f4*)hn;
    f4 hreg[4];
#pragma unroll
    for (int k = 0; k < 4; ++k) hreg[k] = h4[64 * k + lane];
    float m = -INFINITY, s = 0.f;
    for (int v = gw; v < V; v += 4096) {
        const f4* wr = (const f4*)(Wo + (size_t)v * H);
        float acc = 0.f;
#pragma unroll
        for (int k = 0; k < 4; ++k) acc += dot4f(wr[64 * k + lane], hreg[k]);
        acc = wred_sum(acc) + bo[v];
        if (lane == 0) logits[v] = acc;
        float M = fmaxf(m, acc);
        s = s * expf(m - M) + expf(acc - M);
        m = M;
    }
    __shared__ float smm[4], sms[4];
    if (lane == 0) { smm[wv] = m; sms[wv] = s; }
    __syncthreads();
    if (threadIdx.x == 0) {
        float M = smm[0], S = sms[0];
#pragma unroll
        for (int i = 1; i < 4; ++i) ms_merge(M, S, smm[i], sms[i]);
        pm[b] = M; ps[b] = S;
    }
}

// K6 (197 blocks): redundant (m,s) reduce over 1024 partials -> C; subtract.
__global__ void k_finalize(float* __restrict__ out,
                           const float* __restrict__ pm,
                           const float* __restrict__ ps) {
    const int t = threadIdx.x, lane = t & 63, wv = t >> 6;
    float m = -INFINITY, s = 0.f;
    for (int i = t; i < NBGEMV; i += 256) ms_merge(m, s, pm[i], ps[i]);
#pragma unroll
    for (int o = 32; o > 0; o >>= 1) {
        float m2 = __shfl_xor(m, o, 64);
        float s2 = __shfl_xor(s, o, 64);
        ms_merge(m, s, m2, s2);
    }
    __shared__ float smm[4], sms[4];
    __shared__ float Cs;
    if (lane == 0) { smm[wv] = m; sms[wv] = s; }
    __syncthreads();
    if (t == 0) {
        float M = smm[0], S = sms[0];
#pragma unroll
        for (int i = 1; i < 4; ++i) ms_merge(M, S, smm[i], sms[i]);
        Cs = M + logf(S);
    }
    __syncthreads();
    const float C = Cs;
    const int v = blockIdx.x * 256 + t;
    if (v < V) out[v] -= C;
}

extern "C" void kernel_launch(void* const* d_in, const int* in_sizes, int n_in,
                              void* d_out, int out_size, void* d_ws, size_t ws_size,
                              hipStream_t stream) {
    const int*   tok = (const int*)d_in[0];
    const float* hid = (const float*)d_in[1];
    const float* enc = (const float*)d_in[2];
    const float* emb = (const float*)d_in[3];
    const float* Wa  = (const float*)d_in[4];
    const float* ba  = (const float*)d_in[5];
    const float* Wc  = (const float*)d_in[6];
    const float* bc  = (const float*)d_in[7];
    const float* Wih = (const float*)d_in[8];
    const float* Whh = (const float*)d_in[9];
    const float* bih = (const float*)d_in[10];
    const float* bhh = (const float*)d_in[11];
    const float* Wo  = (const float*)d_in[12];
    const float* bo  = (const float*)d_in[13];

    float* out = (float*)d_out;   // [V | H | L]
    float* ws  = (float*)d_ws;
    float* elg  = ws;                 // 512
    float* gh   = ws + 512;           // 3072
    float* aa   = ws + 3584;          // 1024 (16B aligned)
    float* xv   = ws + 4608;          // 1024 (16B aligned)
    float* hn   = ws + 5632;          // 1024 (16B aligned)
    float* pm   = ws + 6656;          // 1024
    float* psum = ws + 7680;          // 1024
    float* pbuf = ws + 8704;          // 256*1024 (16B aligned)

    float* out_logits = out;          // V
    float* out_hnew   = out + V;      // H
    float* out_attnw  = out + V + H;  // L

    k_phase1<<<NPART + 768, 256, 0, stream>>>(tok, hid, emb, Wa, ba, enc, Whh, bhh,
                                              elg, pbuf, gh);
    k_reduce<<<16, 256, 0, stream>>>(elg, pbuf, aa, out_attnw);
    k_comb<<<256, 256, 0, stream>>>(tok, emb, aa, Wc, bc, xv);
    k_gates_gru<<<256, 256, 0, stream>>>(xv, hid, Wih, bih, gh, out_hnew, hn);
    k_out_gemv<<<NBGEMV, 256, 0, stream>>>(hn, Wo, bo, out_logits, pm, psum);
    k_finalize<<<197, 256, 0, stream>>>(out_logits, pm, psum);
}